// Round 3
// baseline (631.723 us; speedup 1.0000x reference)
//
#include <hip/hip_runtime.h>

#define NN 8192
#define FF 256
#define OST 260   // osum LDS row stride in floats

typedef _Float16 h8 __attribute__((ext_vector_type(8)));
typedef _Float16 h4 __attribute__((ext_vector_type(4)));
typedef float    f4 __attribute__((ext_vector_type(4)));
typedef int      i4v __attribute__((ext_vector_type(4)));

// monotone float<->uint encoding for atomicMax on fp32
__device__ __forceinline__ unsigned fenc(float x) {
  unsigned u = __float_as_uint(x);
  return (u & 0x80000000u) ? ~u : (u | 0x80000000u);
}
__device__ __forceinline__ float fdec(unsigned e) {
  unsigned u = (e & 0x80000000u) ? (e ^ 0x80000000u) : ~e;
  return __uint_as_float(u);
}

// ---------------- Kernel 1: Wh = h@W (fp32 vector), s1/s2, wfrag, s2max ------
// grid 256 x 512 thr. Block computes Wh rows [b*32, b*32+32) and emits them in
// MFMA-B-fragment order: wfrag[(kt*16+n)*512 + lane*8 + j].
__global__ __launch_bounds__(512) void k_wh(
    const float* __restrict__ h, const float* __restrict__ W,
    const float* __restrict__ a, _Float16* __restrict__ wfrag,
    float* __restrict__ s1, float* __restrict__ s2,
    unsigned* __restrict__ s2maxe) {
  __shared__ float hs[32 * 256];        // 32 KB
  __shared__ _Float16 whs[32 * 264];    // 16.5 KB
  const int t = threadIdx.x;
  const int r0 = blockIdx.x * 32;
#pragma unroll
  for (int i = 0; i < 4; ++i) {
    int idx = i * 2048 + t * 4;
    *(f4*)&hs[idx] = *(const f4*)&h[(size_t)r0 * 256 + idx];
  }
  __syncthreads();
  const int lane = t & 63;
  const int wv = t >> 6;        // 0..7
  const int rg = wv * 4;        // 4 rows per wave
  const int c4 = lane * 4;      // 4 cols per lane
  float acc[4][4];
#pragma unroll
  for (int i = 0; i < 4; ++i)
#pragma unroll
    for (int k = 0; k < 4; ++k) acc[i][k] = 0.f;
  // rolling W registers, distance-1 prefetch
  f4 w0 = *(const f4*)&W[0 * 256 + c4];
  f4 w1 = *(const f4*)&W[1 * 256 + c4];
  f4 w2 = *(const f4*)&W[2 * 256 + c4];
  f4 w3 = *(const f4*)&W[3 * 256 + c4];
  for (int f = 0; f < 256; f += 4) {
    f4 n0 = w0, n1 = w1, n2 = w2, n3 = w3;
    if (f < 252) {
      n0 = *(const f4*)&W[(f + 4) * 256 + c4];
      n1 = *(const f4*)&W[(f + 5) * 256 + c4];
      n2 = *(const f4*)&W[(f + 6) * 256 + c4];
      n3 = *(const f4*)&W[(f + 7) * 256 + c4];
    }
#pragma unroll
    for (int i = 0; i < 4; ++i) {
      f4 hv = *(const f4*)&hs[(rg + i) * 256 + f];   // wave-uniform LDS broadcast
#pragma unroll
      for (int k = 0; k < 4; ++k)
        acc[i][k] += hv[0] * w0[k] + hv[1] * w1[k] + hv[2] * w2[k] + hv[3] * w3[k];
    }
    w0 = n0; w1 = n1; w2 = n2; w3 = n3;
  }
  float a1v[4], a2v[4];
#pragma unroll
  for (int k = 0; k < 4; ++k) { a1v[k] = a[c4 + k]; a2v[k] = a[256 + c4 + k]; }
#pragma unroll
  for (int i = 0; i < 4; ++i) {
    h4 hh;
    float p1 = 0.f, p2 = 0.f;
#pragma unroll
    for (int k = 0; k < 4; ++k) {
      hh[k] = (_Float16)acc[i][k];
      p1 += acc[i][k] * a1v[k];
      p2 += acc[i][k] * a2v[k];
    }
    *(h4*)&whs[(rg + i) * 264 + c4] = hh;
#pragma unroll
    for (int off = 32; off; off >>= 1) {
      p1 += __shfl_xor(p1, off);
      p2 += __shfl_xor(p2, off);
    }
    if (lane == 0) {
      s1[r0 + rg + i] = p1;
      s2[r0 + rg + i] = p2;
      atomicMax(s2maxe, fenc(p2));
    }
  }
  __syncthreads();
  // emit B-fragments for k-tile kt = blockIdx.x
  {
    const int q = lane >> 4;
    const int m16 = lane & 15;
#pragma unroll
    for (int c = 0; c < 2; ++c) {
      const int n = wv * 2 + c;
      h8 v;
#pragma unroll
      for (int j = 0; j < 8; ++j) v[j] = whs[(q * 8 + j) * 264 + n * 16 + m16];
      *(h8*)&wfrag[(((size_t)blockIdx.x * 16 + n) << 9) + (lane << 3)] = v;
    }
  }
}

// ---------------- Kernel 2: fused masked-softmax attention -------------------
// grid 256 x 512 thr. Block = 32 rows; wave w owns k-tiles w, w+8, ... for all
// rows/cols (no main-loop barriers). P = exp(leaky(s1+s2)-m) computed in regs
// directly in A-frag layout via max(e1*e2, f1*f2) — no exp in inner loop.
// B-loads ping-pong in register batches of 4 (explicit ILP).
__global__ __launch_bounds__(512, 2) void k_gat(
    const int* __restrict__ adj, const _Float16* __restrict__ wfrag,
    const float* __restrict__ s1g, const float* __restrict__ s2g,
    const unsigned* __restrict__ s2maxe, float* __restrict__ out) {
  __shared__ float ef[16384];        // 64 KB: [g*8+0..3]=e2, [g*8+4..7]=f2 (cols 4g..4g+3)
  __shared__ float osum[32 * OST];   // 33.3 KB
  __shared__ float lsh[32];
  const int t = threadIdx.x;
  const int lane = t & 63;
  const int wv = t >> 6;          // 0..7
  const int q = lane >> 4;        // 0..3
  const int m16 = lane & 15;
  const int r0 = blockIdx.x * 32;

  // prologue: tabulate e2/f2, zero osum/lsh
  for (int g = t; g < 2048; g += 512) {
    f4 s2v = *(const f4*)&s2g[g * 4];
    f4 e2v, f2v;
#pragma unroll
    for (int e = 0; e < 4; ++e) {
      e2v[e] = __expf(s2v[e]);
      f2v[e] = __expf(0.2f * s2v[e]);
    }
    *(f4*)&ef[g * 8] = e2v;
    *(f4*)&ef[g * 8 + 4] = f2v;
  }
  for (int i = t; i < 32 * OST; i += 512) osum[i] = 0.f;
  if (t < 32) lsh[t] = 0.f;

  const float s2m = fdec(*s2maxe);
  const float s1a = s1g[r0 + m16];
  const float s1b = s1g[r0 + 16 + m16];
  const float miA = fmaxf(s1a + s2m, 0.2f * (s1a + s2m));
  const float miB = fmaxf(s1b + s2m, 0.2f * (s1b + s2m));
  const float e1a = __expf(s1a - miA), f1a = __expf(0.2f * s1a - miA);
  const float e1b = __expf(s1b - miB), f1b = __expf(0.2f * s1b - miB);
  __syncthreads();

  f4 acc0[16], acc1[16];
#pragma unroll
  for (int n = 0; n < 16; ++n)
#pragma unroll
    for (int e = 0; e < 4; ++e) { acc0[n][e] = 0.f; acc1[n][e] = 0.f; }
  float lsumA = 0.f, lsumB = 0.f;

  const size_t rowA = (size_t)(r0 + m16) * NN;
  const size_t rowB = (size_t)(r0 + 16 + m16) * NN;

  int kt = wv;
  i4v cA0, cA1, cB0, cB1;
  {
    const int k0 = kt * 32 + q * 8;
    cA0 = __builtin_nontemporal_load((const i4v*)&adj[rowA + k0]);
    cA1 = __builtin_nontemporal_load((const i4v*)&adj[rowA + k0 + 4]);
    cB0 = __builtin_nontemporal_load((const i4v*)&adj[rowB + k0]);
    cB1 = __builtin_nontemporal_load((const i4v*)&adj[rowB + k0 + 4]);
  }
  const _Float16* wf = &wfrag[(size_t)kt << 13];
  h8 b0[4], b1[4];
#pragma unroll
  for (int n = 0; n < 4; ++n) b0[n] = *(const h8*)&wf[(n << 9) + (lane << 3)];

  for (int it = 0; it < 32; ++it) {
    // scores for this k-tile: p = max(e1*e2, f1*f2), masked
    const int g = kt * 8 + q * 2;
    f4 e2lo = *(const f4*)&ef[g * 8];
    f4 f2lo = *(const f4*)&ef[g * 8 + 4];
    f4 e2hi = *(const f4*)&ef[g * 8 + 8];
    f4 f2hi = *(const f4*)&ef[g * 8 + 12];
    float pA[8], pB[8];
#pragma unroll
    for (int j = 0; j < 4; ++j) {
      float a_ = fmaxf(e1a * e2lo[j], f1a * f2lo[j]);
      float b_ = fmaxf(e1b * e2lo[j], f1b * f2lo[j]);
      a_ = (cA0[j] > 0) ? a_ : 0.f;
      b_ = (cB0[j] > 0) ? b_ : 0.f;
      pA[j] = a_; pB[j] = b_; lsumA += a_; lsumB += b_;
    }
#pragma unroll
    for (int j = 0; j < 4; ++j) {
      float a_ = fmaxf(e1a * e2hi[j], f1a * f2hi[j]);
      float b_ = fmaxf(e1b * e2hi[j], f1b * f2hi[j]);
      a_ = (cA1[j] > 0) ? a_ : 0.f;
      b_ = (cB1[j] > 0) ? b_ : 0.f;
      pA[j + 4] = a_; pB[j + 4] = b_; lsumA += a_; lsumB += b_;
    }
    // prefetch next tile's adj (distance 1, ~full iteration of cover)
    const int ktn = kt + 8;
    i4v nA0 = cA0, nA1 = cA1, nB0 = cB0, nB1 = cB1;
    if (it < 31) {
      const int k0n = ktn * 32 + q * 8;
      nA0 = __builtin_nontemporal_load((const i4v*)&adj[rowA + k0n]);
      nA1 = __builtin_nontemporal_load((const i4v*)&adj[rowA + k0n + 4]);
      nB0 = __builtin_nontemporal_load((const i4v*)&adj[rowB + k0n]);
      nB1 = __builtin_nontemporal_load((const i4v*)&adj[rowB + k0n + 4]);
    }
    h8 afA, afB;
#pragma unroll
    for (int j = 0; j < 8; ++j) { afA[j] = (_Float16)pA[j]; afB[j] = (_Float16)pB[j]; }

    const _Float16* wfn = &wfrag[(size_t)ktn << 13];
    // ping-pong MFMA/load batches of 4 n-tiles: 4 loads always in flight
#pragma unroll
    for (int n = 0; n < 4; ++n) b1[n] = *(const h8*)&wf[((n + 4) << 9) + (lane << 3)];
#pragma unroll
    for (int n = 0; n < 4; ++n) {
      acc0[n] = __builtin_amdgcn_mfma_f32_16x16x32_f16(afA, b0[n], acc0[n], 0, 0, 0);
      acc1[n] = __builtin_amdgcn_mfma_f32_16x16x32_f16(afB, b0[n], acc1[n], 0, 0, 0);
    }
#pragma unroll
    for (int n = 0; n < 4; ++n) b0[n] = *(const h8*)&wf[((n + 8) << 9) + (lane << 3)];
#pragma unroll
    for (int n = 0; n < 4; ++n) {
      acc0[n + 4] = __builtin_amdgcn_mfma_f32_16x16x32_f16(afA, b1[n], acc0[n + 4], 0, 0, 0);
      acc1[n + 4] = __builtin_amdgcn_mfma_f32_16x16x32_f16(afB, b1[n], acc1[n + 4], 0, 0, 0);
    }
#pragma unroll
    for (int n = 0; n < 4; ++n) b1[n] = *(const h8*)&wf[((n + 12) << 9) + (lane << 3)];
#pragma unroll
    for (int n = 0; n < 4; ++n) {
      acc0[n + 8] = __builtin_amdgcn_mfma_f32_16x16x32_f16(afA, b0[n], acc0[n + 8], 0, 0, 0);
      acc1[n + 8] = __builtin_amdgcn_mfma_f32_16x16x32_f16(afB, b0[n], acc1[n + 8], 0, 0, 0);
    }
    if (it < 31) {
#pragma unroll
      for (int n = 0; n < 4; ++n) b0[n] = *(const h8*)&wfn[(n << 9) + (lane << 3)];
    }
#pragma unroll
    for (int n = 0; n < 4; ++n) {
      acc0[n + 12] = __builtin_amdgcn_mfma_f32_16x16x32_f16(afA, b1[n], acc0[n + 12], 0, 0, 0);
      acc1[n + 12] = __builtin_amdgcn_mfma_f32_16x16x32_f16(afB, b1[n], acc1[n + 12], 0, 0, 0);
    }
    cA0 = nA0; cA1 = nA1; cB0 = nB0; cB1 = nB1;
    kt = ktn; wf = wfn;
  }

  // softmax denominators: reduce q-groups, then across waves
  lsumA += __shfl_xor(lsumA, 16); lsumA += __shfl_xor(lsumA, 32);
  lsumB += __shfl_xor(lsumB, 16); lsumB += __shfl_xor(lsumB, 32);
  if (q == 0) {
    atomicAdd(&lsh[m16], lsumA);
    atomicAdd(&lsh[16 + m16], lsumB);
  }
  // partial-O reduce across waves (C layout: col=lane&15, row=q*4+reg)
#pragma unroll
  for (int n = 0; n < 16; ++n)
#pragma unroll
    for (int v = 0; v < 4; ++v) {
      atomicAdd(&osum[(q * 4 + v) * OST + n * 16 + m16], acc0[n][v]);
      atomicAdd(&osum[(16 + q * 4 + v) * OST + n * 16 + m16], acc1[n][v]);
    }
  __syncthreads();

  // epilogue: out = elu(O / l), coalesced f4 stores
  const int row = t >> 4;
  const int c0 = (t & 15) * 16;
  const float linv = 1.0f / lsh[row];
#pragma unroll
  for (int i = 0; i < 4; ++i) {
    f4 v = *(const f4*)&osum[row * OST + c0 + i * 4];
    f4 o;
#pragma unroll
    for (int e = 0; e < 4; ++e) {
      float x = v[e] * linv;
      o[e] = (x > 0.f) ? x : (__expf(x) - 1.f);
    }
    *(f4*)&out[(size_t)(r0 + row) * FF + c0 + i * 4] = o;
  }
}

extern "C" void kernel_launch(void* const* d_in, const int* in_sizes, int n_in,
                              void* d_out, int out_size, void* d_ws, size_t ws_size,
                              hipStream_t stream) {
  const float* h   = (const float*)d_in[0];
  const int*   adj = (const int*)d_in[1];
  const float* W   = (const float*)d_in[2];
  const float* a   = (const float*)d_in[3];
  float* out = (float*)d_out;

  char* ws = (char*)d_ws;
  _Float16* wfrag = (_Float16*)ws;                          // 4 MB: Wh in B-frag order
  float* s1       = (float*)(ws + 4u * 1024 * 1024);        // 32 KB
  float* s2       = (float*)(ws + 4u * 1024 * 1024 + 32768);// 32 KB
  unsigned* s2me  = (unsigned*)(ws + 4u * 1024 * 1024 + 65536); // 4 B

  hipMemsetAsync(s2me, 0, 4, stream);   // fenc-domain -inf
  k_wh<<<256, 512, 0, stream>>>(h, W, a, wfrag, s1, s2, s2me);
  k_gat<<<256, 512, 0, stream>>>(adj, wfrag, s1, s2, s2me, out);
}

// Round 4
// 620.792 us; speedup vs baseline: 1.0176x; 1.0176x over previous
//
#include <hip/hip_runtime.h>

#define NN 8192
#define FF 256
#define OST 132   // osum LDS row stride (16 rows x 128 cols + pad)

typedef _Float16 h8 __attribute__((ext_vector_type(8)));
typedef _Float16 h4 __attribute__((ext_vector_type(4)));
typedef float    f4 __attribute__((ext_vector_type(4)));
typedef int      i4v __attribute__((ext_vector_type(4)));

// monotone float<->uint encoding for atomicMax on fp32
__device__ __forceinline__ unsigned fenc(float x) {
  unsigned u = __float_as_uint(x);
  return (u & 0x80000000u) ? ~u : (u | 0x80000000u);
}
__device__ __forceinline__ float fdec(unsigned e) {
  unsigned u = (e & 0x80000000u) ? (e ^ 0x80000000u) : ~e;
  return __uint_as_float(u);
}

// ---------------- Kernel 1: Wh = h@W (fp32 vector), s1, ef16 tables, wfrag ---
// grid 512 x 256 thr. Block = 16 rows of h = half of k-tile (blockIdx>>1) of
// the PV matmul. Emits Wh in MFMA-B-fragment order:
//   wfrag[(kt*16+n)*512 + lane*8 + j] = Wh[kt*32 + (lane>>4)*8 + j][n*16 + (lane&15)]
__global__ __launch_bounds__(256) void k_wh(
    const float* __restrict__ h, const float* __restrict__ W,
    const float* __restrict__ a, _Float16* __restrict__ wfrag,
    float* __restrict__ s1, _Float16* __restrict__ ef2h,
    unsigned* __restrict__ s2maxe) {
  __shared__ float hs[16 * 256];        // 16 KB
  __shared__ _Float16 whs[16 * 264];    // 8.25 KB
  const int t = threadIdx.x;
  const int r0 = blockIdx.x * 16;
#pragma unroll
  for (int i = 0; i < 4; ++i) {
    int idx = i * 1024 + t * 4;
    *(f4*)&hs[idx] = *(const f4*)&h[(size_t)r0 * 256 + idx];
  }
  __syncthreads();
  const int lane = t & 63;
  const int wv = t >> 6;        // 0..3
  const int rg = wv * 4;        // 4 rows per wave
  const int c4 = lane * 4;      // 4 cols per lane
  float acc[4][4];
#pragma unroll
  for (int i = 0; i < 4; ++i)
#pragma unroll
    for (int k = 0; k < 4; ++k) acc[i][k] = 0.f;
  // depth-2 rolling W prefetch: 8 rows in flight
  f4 w[8];
#pragma unroll
  for (int i = 0; i < 8; ++i) w[i] = *(const f4*)&W[i * 256 + c4];
  for (int f = 0; f < 256; f += 8) {
    f4 nw[8];
    if (f < 248) {
#pragma unroll
      for (int i = 0; i < 8; ++i) nw[i] = *(const f4*)&W[(f + 8 + i) * 256 + c4];
    }
#pragma unroll
    for (int i = 0; i < 4; ++i) {
      f4 h0 = *(const f4*)&hs[(rg + i) * 256 + f];       // wave-uniform broadcast
      f4 h1 = *(const f4*)&hs[(rg + i) * 256 + f + 4];
#pragma unroll
      for (int k = 0; k < 4; ++k)
        acc[i][k] += h0[0]*w[0][k] + h0[1]*w[1][k] + h0[2]*w[2][k] + h0[3]*w[3][k]
                   + h1[0]*w[4][k] + h1[1]*w[5][k] + h1[2]*w[6][k] + h1[3]*w[7][k];
    }
    if (f < 248) {
#pragma unroll
      for (int i = 0; i < 8; ++i) w[i] = nw[i];
    }
  }
  float a1v[4], a2v[4];
#pragma unroll
  for (int k = 0; k < 4; ++k) { a1v[k] = a[c4 + k]; a2v[k] = a[256 + c4 + k]; }
#pragma unroll
  for (int i = 0; i < 4; ++i) {
    h4 hh;
    float p1 = 0.f, p2 = 0.f;
#pragma unroll
    for (int k = 0; k < 4; ++k) {
      hh[k] = (_Float16)acc[i][k];
      p1 += acc[i][k] * a1v[k];
      p2 += acc[i][k] * a2v[k];
    }
    *(h4*)&whs[(rg + i) * 264 + c4] = hh;
#pragma unroll
    for (int off = 32; off; off >>= 1) {
      p1 += __shfl_xor(p1, off);
      p2 += __shfl_xor(p2, off);
    }
    if (lane == 0) {
      const int r = r0 + rg + i;
      s1[r] = p1;
      atomicMax(s2maxe, fenc(p2));
      // unshifted exp tables: |s2| <~ 9 -> exp(s2) <~ 8e3, fits f16
      ef2h[2 * r]     = (_Float16)__expf(p2);
      ef2h[2 * r + 1] = (_Float16)__expf(0.2f * p2);
    }
  }
  __syncthreads();
  // emit B-fragments: this block covers k-half hb of k-tile kt
  {
    const int kt = blockIdx.x >> 1;
    const int hb = blockIdx.x & 1;
    const int lp = hb * 32 + (t & 31);     // target frag lane
    const int kb = ((t & 31) >> 4) * 8;    // local k base (0 or 8)
    const int m16e = t & 15;
#pragma unroll
    for (int p = 0; p < 2; ++p) {
      const int n = (t >> 5) + p * 8;
      h8 v;
#pragma unroll
      for (int j = 0; j < 8; ++j) v[j] = whs[(kb + j) * 264 + n * 16 + m16e];
      *(h8*)&wfrag[(((size_t)kt * 16 + n) << 9) + lp * 8] = v;
    }
  }
}

// ---------------- Kernel 2: fused masked-softmax attention -------------------
// grid 1024 x 256 thr = 512 row-tiles (16 rows) x 2 col-halves (128 cols),
// swizzled so both col-halves of a row-tile share an XCD (adj L2 reuse).
// Wave wk owns k-quarter [wk*2048, +2048) for all 16 rows x 128 cols: no
// main-loop barriers, no cross-wave score redundancy. Issue order per iter is
// vmcnt-clean: [b1][slow kt+1][scores][mfma b0][b0 kt+1][mfma b1].
__global__ __launch_bounds__(256, 4) void k_gat(
    const int* __restrict__ adj, const _Float16* __restrict__ wfrag,
    const float* __restrict__ s1g, const _Float16* __restrict__ ef2h,
    const unsigned* __restrict__ s2maxe, float* __restrict__ out) {
  __shared__ float osum[16 * OST];   // 8.4 KB
  __shared__ float lsh[16];
  const int t = threadIdx.x;
  const int lane = t & 63;
  const int wk = t >> 6;          // 0..3: k-quarter
  const int q = lane >> 4;        // 0..3
  const int m16 = lane & 15;
  const int b = blockIdx.x;
  const int c = (b >> 3) & 1;                   // col-half
  const int rt = (b & 7) | ((b >> 4) << 3);     // row-tile 0..511
  const int r0 = rt * 16;

  for (int i = t; i < 16 * OST; i += 256) osum[i] = 0.f;
  if (t < 16) lsh[t] = 0.f;
  __syncthreads();

  const float s2m = fdec(*s2maxe);
  const float s1a = s1g[r0 + m16];
  const float u0 = s1a + s2m;
  const float mi = fmaxf(u0, 0.2f * u0);        // upper bound on row scores
  const float e1a = __expf(s1a - mi), f1a = __expf(0.2f * s1a - mi);

  f4 acc[8];
#pragma unroll
  for (int n = 0; n < 8; ++n)
#pragma unroll
    for (int e = 0; e < 4; ++e) acc[n][e] = 0.f;
  float lsum = 0.f;

  const int* adjrow = adj + (size_t)(r0 + m16) * NN + q * 8;
  int kt = wk * 64;

  // preload: slow set (adj+ef) and b batch0 for first kt
  i4v ajc0 = *(const i4v*)(adjrow + kt * 32);
  i4v ajc1 = *(const i4v*)(adjrow + kt * 32 + 4);
  h8 efc0 = *(const h8*)&ef2h[kt * 64 + q * 16];
  h8 efc1 = *(const h8*)&ef2h[kt * 64 + q * 16 + 8];
  h8 b0[4], b1[4];
  {
    const _Float16* wfc = wfrag + (((size_t)kt * 16 + c * 8) << 9) + lane * 8;
#pragma unroll
    for (int n = 0; n < 4; ++n) b0[n] = *(const h8*)(wfc + n * 512);
  }

  for (int it = 0; it < 64; ++it) {
    const _Float16* wfc = wfrag + (((size_t)kt * 16 + c * 8) << 9) + lane * 8;
    // (0) b batch1 for kt
#pragma unroll
    for (int n = 0; n < 4; ++n) b1[n] = *(const h8*)(wfc + (n + 4) * 512);
    // (1) slow prefetch for kt+1 (HBM adj + L2 ef) — issued after b1 so b1's
    // wait never drains them; consumed next iter (~1 full iter of cover)
    i4v ajn0 = ajc0, ajn1 = ajc1; h8 efn0 = efc0, efn1 = efc1;
    if (it < 63) {
      ajn0 = *(const i4v*)(adjrow + (kt + 1) * 32);
      ajn1 = *(const i4v*)(adjrow + (kt + 1) * 32 + 4);
      efn0 = *(const h8*)&ef2h[(kt + 1) * 64 + q * 16];
      efn1 = *(const h8*)&ef2h[(kt + 1) * 64 + q * 16 + 8];
    }
    // (2) scores for kt: p = max(e1*e2, f1*f2) masked; A-frag layout
    h8 af;
#pragma unroll
    for (int j = 0; j < 8; ++j) {
      const float ee = (float)((j < 4) ? efc0[2 * j] : efc1[2 * (j - 4)]);
      const float ff = (float)((j < 4) ? efc0[2 * j + 1] : efc1[2 * (j - 4) + 1]);
      const int msk = (j < 4) ? ajc0[j] : ajc1[j - 4];
      const float p = (msk > 0) ? fmaxf(e1a * ee, f1a * ff) : 0.f;
      lsum += p;
      af[j] = (_Float16)p;
    }
    // (3) MFMA batch0 (b0 loaded last iter, ~1 iter old)
#pragma unroll
    for (int n = 0; n < 4; ++n)
      acc[n] = __builtin_amdgcn_mfma_f32_16x16x32_f16(af, b0[n], acc[n], 0, 0, 0);
    // (4) preload batch0 for kt+1
    if (it < 63) {
      const _Float16* wfn = wfrag + (((size_t)(kt + 1) * 16 + c * 8) << 9) + lane * 8;
#pragma unroll
      for (int n = 0; n < 4; ++n) b0[n] = *(const h8*)(wfn + n * 512);
    }
    // (5) MFMA batch1 (b1 issued this iter before slow set)
#pragma unroll
    for (int n = 0; n < 4; ++n)
      acc[n + 4] = __builtin_amdgcn_mfma_f32_16x16x32_f16(af, b1[n], acc[n + 4], 0, 0, 0);
    // (6) rotate slow regs
    ajc0 = ajn0; ajc1 = ajn1; efc0 = efn0; efc1 = efn1;
    ++kt;
  }

  // denominators: combine q-groups (same row class m16), then across waves
  lsum += __shfl_xor(lsum, 16);
  lsum += __shfl_xor(lsum, 32);
  if (q == 0) atomicAdd(&lsh[m16], lsum);
  // partial-O reduce across waves (C layout: col=lane&15, row=q*4+reg)
#pragma unroll
  for (int n = 0; n < 8; ++n)
#pragma unroll
    for (int v = 0; v < 4; ++v)
      atomicAdd(&osum[(q * 4 + v) * OST + n * 16 + m16], acc[n][v]);
  __syncthreads();

  // epilogue: out = elu(O / l); block writes its 16x128 col-slice
  const int row = t >> 4;
  const int c0 = (t & 15) * 8;
  const float linv = 1.0f / lsh[row];
#pragma unroll
  for (int i = 0; i < 2; ++i) {
    f4 v = *(const f4*)&osum[row * OST + c0 + i * 4];
    f4 o;
#pragma unroll
    for (int e = 0; e < 4; ++e) {
      float x = v[e] * linv;
      o[e] = (x > 0.f) ? x : (__expf(x) - 1.f);
    }
    *(f4*)&out[(size_t)(r0 + row) * FF + c * 128 + c0 + i * 4] = o;
  }
}

extern "C" void kernel_launch(void* const* d_in, const int* in_sizes, int n_in,
                              void* d_out, int out_size, void* d_ws, size_t ws_size,
                              hipStream_t stream) {
  const float* h   = (const float*)d_in[0];
  const int*   adj = (const int*)d_in[1];
  const float* W   = (const float*)d_in[2];
  const float* a   = (const float*)d_in[3];
  float* out = (float*)d_out;

  char* ws = (char*)d_ws;
  _Float16* wfrag = (_Float16*)ws;                            // 4 MB
  float*    s1    = (float*)(ws + 4u * 1024 * 1024);          // 32 KB
  _Float16* ef2h  = (_Float16*)(ws + 4u * 1024 * 1024 + 32768); // 32 KB
  unsigned* s2me  = (unsigned*)(ws + 4u * 1024 * 1024 + 65536); // 4 B

  hipMemsetAsync(s2me, 0, 4, stream);   // fenc-domain -inf
  k_wh<<<512, 256, 0, stream>>>(h, W, a, wfrag, s1, ef2h, s2me);
  k_gat<<<1024, 256, 0, stream>>>(adj, wfrag, s1, ef2h, s2me, out);
}